// Round 6
// baseline (1813.567 us; speedup 1.0000x reference)
//
#include <hip/hip_runtime.h>

#define DIM 64
#define NPW 8         // nodes per wave in k_layer (2 batches of 4)
#define NB_SHIFT 8    // 256 nodes per bucket
#define NB 256
#define BMAX 1024     // max buckets supported (N <= 262144)
#define TILE 4096     // edges per binB block
#define EPT 16        // TILE / 256

// ---------------- bucketed CSR build ----------------

// Pass A: count edges per destination bucket (LDS-aggregated).
__global__ __launch_bounds__(256) void k_binA(const int* __restrict__ dst, int E, int B,
                                              int* __restrict__ bucketCnt) {
    __shared__ int cntL[BMAX];
    int t = threadIdx.x;
    for (int j = t; j < B; j += 256) cntL[j] = 0;
    __syncthreads();
    int stride = gridDim.x * 256;
    for (int i = blockIdx.x * 256 + t; i < E; i += stride)
        atomicAdd(&cntL[dst[i] >> NB_SHIFT], 1);
    __syncthreads();
    for (int j = t; j < B; j += 256)
        if (cntL[j]) atomicAdd(&bucketCnt[j], cntL[j]);
}

// Pass A2: exclusive scan of bucket counts (one block).
__global__ __launch_bounds__(256) void k_scanB(const int* __restrict__ bucketCnt, int B, int E, int N,
                                               int* __restrict__ bucketOff,
                                               int* __restrict__ bucketCursor,
                                               int* __restrict__ row_ptr) {
    __shared__ int sdata[256];
    int t = threadIdx.x;
    int i0 = 2 * t, i1 = 2 * t + 1;
    int a0 = (i0 < B) ? bucketCnt[i0] : 0;
    int a1 = (i1 < B) ? bucketCnt[i1] : 0;
    int s = a0 + a1;
    sdata[t] = s;
    __syncthreads();
    for (int off = 1; off < 256; off <<= 1) {
        int tmp = (t >= off) ? sdata[t - off] : 0;
        __syncthreads();
        if (t >= off) sdata[t] += tmp;
        __syncthreads();
    }
    int excl = sdata[t] - s;
    if (i0 <= B) { bucketOff[i0] = excl; if (i0 < B) bucketCursor[i0] = excl; }
    int o1 = excl + a0;
    if (i1 <= B) { bucketOff[i1] = o1; if (i1 < B) bucketCursor[i1] = o1; }
    if (t == 0) row_ptr[N] = E;
}

// Pass B: scatter packed edges (localNode<<17 | src) into bucket-contiguous regions.
__global__ __launch_bounds__(256) void k_binB(const int* __restrict__ src, const int* __restrict__ dst,
                                              int E, int B, int* __restrict__ bucketCursor,
                                              int* __restrict__ pairs) {
    __shared__ int cntL[BMAX];
    __shared__ int baseL[BMAX];
    int t = threadIdx.x;
    for (int j = t; j < B; j += 256) cntL[j] = 0;
    __syncthreads();
    int tile0 = blockIdx.x * TILE;
    int s_[EPT], d_[EPT], o_[EPT];
#pragma unroll
    for (int j = 0; j < EPT; ++j) {
        int i = tile0 + j * 256 + t;
        if (i < E) {
            s_[j] = src[i];
            d_[j] = dst[i];
            o_[j] = atomicAdd(&cntL[d_[j] >> NB_SHIFT], 1);
        } else {
            d_[j] = -1;
        }
    }
    __syncthreads();
    for (int j = t; j < B; j += 256)
        if (cntL[j]) baseL[j] = atomicAdd(&bucketCursor[j], cntL[j]);
    __syncthreads();
#pragma unroll
    for (int j = 0; j < EPT; ++j) {
        if (d_[j] >= 0) {
            int b = d_[j] >> NB_SHIFT;
            pairs[baseL[b] + o_[j]] = ((d_[j] & (NB - 1)) << 17) | s_[j];
        }
    }
}

// Pass C: per-bucket local CSR build in LDS; emits row_ptr, col, dinv, and Xs = x*dinv (fused prep).
__global__ __launch_bounds__(256) void k_buildCSR(const int* __restrict__ pairs,
                                                  const int* __restrict__ bucketOff,
                                                  int N, int* __restrict__ row_ptr,
                                                  int* __restrict__ col,
                                                  float* __restrict__ dinv,
                                                  const float* __restrict__ x,
                                                  float* __restrict__ Xs) {
    __shared__ int cntL[NB];
    __shared__ int sdata[NB];
    __shared__ int curL[NB];
    __shared__ float dinvL[NB];
    int t = threadIdx.x;
    int b = blockIdx.x;
    int nodeBase = b << NB_SHIFT;
    int nNodes = N - nodeBase; if (nNodes > NB) nNodes = NB;
    int e0 = bucketOff[b], e1 = bucketOff[b + 1];
    cntL[t] = 0;
    __syncthreads();
    for (int i = e0 + t; i < e1; i += 256)
        atomicAdd(&cntL[pairs[i] >> 17], 1);
    __syncthreads();
    int c = cntL[t];
    sdata[t] = c;
    __syncthreads();
    for (int off = 1; off < 256; off <<= 1) {
        int tmp = (t >= off) ? sdata[t - off] : 0;
        __syncthreads();
        if (t >= off) sdata[t] += tmp;
        __syncthreads();
    }
    int excl = sdata[t] - c;
    float dv = rsqrtf((float)(c + 1));
    if (t < nNodes) {
        row_ptr[nodeBase + t] = e0 + excl;
        dinv[nodeBase + t] = dv;
    }
    dinvL[t] = dv;
    curL[t] = excl;
    __syncthreads();
    for (int i = e0 + t; i < e1; i += 256) {
        int p = pairs[i];
        int l = p >> 17;
        int slot = atomicAdd(&curL[l], 1);
        col[e0 + slot] = p & 0x1FFFF;
    }
    // fused prep: Xs[v,:] = x[v,:] * dinv[v] for this bucket's nodes
    int total = nNodes * DIM;
    int base64 = nodeBase << 6;
    for (int i = t; i < total; i += 256)
        Xs[base64 + i] = x[base64 + i] * dinvL[i >> 6];
}

// ---------------- fused layer ----------------
// z_j = In[v_j] + sum_{u in CSR[v_j]} In[u]   (quad-group float4 gather, 4 loads in flight)
// h_j = dinv[v_j]*(z_j @ W) + b ; Out = SCALE_OUT ? dinv*act(h) : act(h)
// Epilogue batches 4 nodes: z_j staged to LDS (1 write/node), then one pass over W
// reuses each WL4 read for 4 nodes (WL4 b128 reads per node: 16 -> 4).
template <bool RELU, bool SCALE_OUT>
__global__ __launch_bounds__(256, 8) void k_layer(const float* __restrict__ In,
                                                  const int* __restrict__ row_ptr,
                                                  const int* __restrict__ col,
                                                  const float* __restrict__ dinv,
                                                  const float* __restrict__ W,
                                                  const float* __restrict__ bias,
                                                  float* __restrict__ Out, int N) {
    __shared__ float WLs[DIM * DIM];   // 16 KB: WLs[k16*256 + col*4 + j] = W[4*k16+j][col]
    __shared__ float4 zS[4 * 64];      // 4 KB: per wave, 4 nodes x 16 chunks
    int t = threadIdx.x;
    int lane = t & 63;
    int wave = t >> 6;
    int g = lane >> 4;    // quad group 0..3
    int gl = lane & 15;   // float4 index within a row

    // stage W transposed-quad (coalesced global reads)
    for (int k = wave; k < DIM; k += 4)
        WLs[(k >> 2) * 256 + lane * 4 + (k & 3)] = W[k * DIM + lane];
    __syncthreads();
    const float4* WL4 = (const float4*)WLs;   // WL4[k16*64 + col] = {W[4*k16+j][col]}_j

    float blane = bias[lane];
    const float4* InR = (const float4*)In;    // 16 float4 per row

    int v0 = (blockIdx.x * 4 + wave) * NPW;
    for (int rb = 0; rb < NPW / 4; ++rb) {
        int vb = v0 + rb * 4;
        if (vb >= N) return;
        float dvv[4];
        // ---- gather phase: 4 nodes, z staged to zS ----
        for (int j = 0; j < 4; ++j) {
            int v = vb + j;
            int vc = (v < N) ? v : (N - 1);
            int e0 = row_ptr[vc];
            int e1 = row_ptr[vc + 1];
            dvv[j] = dinv[vc];
            int d1 = e1 - e0 + 1;  // neighbors + self
            float4 acc0 = make_float4(0.f, 0.f, 0.f, 0.f);
            float4 acc1 = make_float4(0.f, 0.f, 0.f, 0.f);
            float4 acc2 = make_float4(0.f, 0.f, 0.f, 0.f);
            float4 acc3 = make_float4(0.f, 0.f, 0.f, 0.f);
            int base = 0;
            while (base < d1) {
                int m = d1 - base; if (m > 64) m = 64;
                int slot = base + lane;
                int u = vc;
                if (slot > 0 && slot < d1) u = col[e0 + slot - 1];
                int nfull = m >> 2;
                int q = 0;
                for (; q + 4 <= nfull; q += 4) {
                    int u0 = __shfl(u, (q + 0) * 4 + g, 64);
                    int u1 = __shfl(u, (q + 1) * 4 + g, 64);
                    int u2 = __shfl(u, (q + 2) * 4 + g, 64);
                    int u3 = __shfl(u, (q + 3) * 4 + g, 64);
                    float4 a0 = InR[u0 * 16 + gl];
                    float4 a1 = InR[u1 * 16 + gl];
                    float4 a2 = InR[u2 * 16 + gl];
                    float4 a3 = InR[u3 * 16 + gl];
                    acc0.x += a0.x; acc0.y += a0.y; acc0.z += a0.z; acc0.w += a0.w;
                    acc1.x += a1.x; acc1.y += a1.y; acc1.z += a1.z; acc1.w += a1.w;
                    acc2.x += a2.x; acc2.y += a2.y; acc2.z += a2.z; acc2.w += a2.w;
                    acc3.x += a3.x; acc3.y += a3.y; acc3.z += a3.z; acc3.w += a3.w;
                }
                for (; q + 2 <= nfull; q += 2) {
                    int u0 = __shfl(u, (q + 0) * 4 + g, 64);
                    int u1 = __shfl(u, (q + 1) * 4 + g, 64);
                    float4 a0 = InR[u0 * 16 + gl];
                    float4 a1 = InR[u1 * 16 + gl];
                    acc0.x += a0.x; acc0.y += a0.y; acc0.z += a0.z; acc0.w += a0.w;
                    acc1.x += a1.x; acc1.y += a1.y; acc1.z += a1.z; acc1.w += a1.w;
                }
                for (; q < nfull; ++q) {
                    int u0 = __shfl(u, q * 4 + g, 64);
                    float4 a0 = InR[u0 * 16 + gl];
                    acc0.x += a0.x; acc0.y += a0.y; acc0.z += a0.z; acc0.w += a0.w;
                }
                if (m & 3) {
                    int sidx = nfull * 4 + g;
                    bool ok = sidx < m;
                    int uu = __shfl(u, ok ? sidx : 0, 64);
                    float4 a0 = InR[uu * 16 + gl];
                    if (ok) { acc0.x += a0.x; acc0.y += a0.y; acc0.z += a0.z; acc0.w += a0.w; }
                }
                base += m;
            }
            float4 z;
            z.x = (acc0.x + acc1.x) + (acc2.x + acc3.x);
            z.y = (acc0.y + acc1.y) + (acc2.y + acc3.y);
            z.z = (acc0.z + acc1.z) + (acc2.z + acc3.z);
            z.w = (acc0.w + acc1.w) + (acc2.w + acc3.w);
            // cross-group reduce: every lane gets full z[4*gl..4*gl+3]
            z.x += __shfl_xor(z.x, 16, 64); z.y += __shfl_xor(z.y, 16, 64);
            z.z += __shfl_xor(z.z, 16, 64); z.w += __shfl_xor(z.w, 16, 64);
            z.x += __shfl_xor(z.x, 32, 64); z.y += __shfl_xor(z.y, 32, 64);
            z.z += __shfl_xor(z.z, 32, 64); z.w += __shfl_xor(z.w, 32, 64);
            if (g == 0) zS[wave * 64 + j * 16 + gl] = z;  // intra-wave, no barrier
        }
        // ---- batched epilogue: one W pass for 4 nodes ----
        float r0 = 0.f, r1 = 0.f, r2 = 0.f, r3 = 0.f;
#pragma unroll
        for (int k16 = 0; k16 < 16; ++k16) {
            float4 wv = WL4[k16 * 64 + lane];
            float4 z0 = zS[wave * 64 + 0 * 16 + k16];  // broadcast reads
            float4 z1 = zS[wave * 64 + 1 * 16 + k16];
            float4 z2 = zS[wave * 64 + 2 * 16 + k16];
            float4 z3 = zS[wave * 64 + 3 * 16 + k16];
            r0 = fmaf(z0.x, wv.x, fmaf(z0.y, wv.y, fmaf(z0.z, wv.z, fmaf(z0.w, wv.w, r0))));
            r1 = fmaf(z1.x, wv.x, fmaf(z1.y, wv.y, fmaf(z1.z, wv.z, fmaf(z1.w, wv.w, r1))));
            r2 = fmaf(z2.x, wv.x, fmaf(z2.y, wv.y, fmaf(z2.z, wv.z, fmaf(z2.w, wv.w, r2))));
            r3 = fmaf(z3.x, wv.x, fmaf(z3.y, wv.y, fmaf(z3.z, wv.z, fmaf(z3.w, wv.w, r3))));
        }
        float rr[4] = {r0, r1, r2, r3};
#pragma unroll
        for (int j = 0; j < 4; ++j) {
            int v = vb + j;
            if (v < N) {
                float h = fmaf(dvv[j], rr[j], blane);
                if (RELU) h = fmaxf(h, 0.f);
                if (SCALE_OUT) h *= dvv[j];
                Out[v * DIM + lane] = h;
            }
        }
    }
}

// ---------------- pooling + head ----------------

__global__ __launch_bounds__(256) void k_pool(const float* __restrict__ H, const int* __restrict__ batch,
                                              int N, float* __restrict__ sums, int chunk) {
    int t = threadIdx.x;
    int lane = t & 63;
    int start = (blockIdx.x * 4 + (t >> 6)) * chunk;
    int end = start + chunk; if (end > N) end = N;
    if (start >= end) return;
    float acc = 0.f;
    int cur = batch[start];
    for (int i = start; i < end; ++i) {
        int b = batch[i];
        if (b != cur) {
            atomicAdd(&sums[cur * DIM + lane], acc);
            acc = 0.f; cur = b;
        }
        acc += H[i * DIM + lane];
    }
    atomicAdd(&sums[cur * DIM + lane], acc);
}

__global__ __launch_bounds__(64) void k_final(const float* __restrict__ sums,
                                              const int* __restrict__ batch, int N,
                                              const float* __restrict__ Wlin,
                                              const float* __restrict__ blin,
                                              float* __restrict__ out) {
    int g = blockIdx.x;
    int j = threadIdx.x;
    int lo = 0, hi = N;
    while (lo < hi) { int mid = (lo + hi) >> 1; if (batch[mid] < g) lo = mid + 1; else hi = mid; }
    int c0 = lo;
    lo = 0; hi = N;
    int g1 = g + 1;
    while (lo < hi) { int mid = (lo + hi) >> 1; if (batch[mid] < g1) lo = mid + 1; else hi = mid; }
    int c1 = lo;
    int c = c1 - c0; if (c < 1) c = 1;
    float invc = 1.0f / (float)c;
    float acc = 0.f;
#pragma unroll
    for (int k = 0; k < DIM; ++k)
        acc = fmaf(sums[g * DIM + k] * invc, Wlin[k * DIM + j], acc);
    out[g * DIM + j] = acc + blin[j];
}

// ---------------- launch ----------------

extern "C" void kernel_launch(void* const* d_in, const int* in_sizes, int n_in,
                              void* d_out, int out_size, void* d_ws, size_t ws_size,
                              hipStream_t stream) {
    const float* x    = (const float*)d_in[0];
    const int*   edge = (const int*)d_in[1];
    const int*   batch= (const int*)d_in[2];
    const float* W1 = (const float*)d_in[3];
    const float* b1 = (const float*)d_in[4];
    const float* W2 = (const float*)d_in[5];
    const float* b2 = (const float*)d_in[6];
    const float* W3 = (const float*)d_in[7];
    const float* b3 = (const float*)d_in[8];
    const float* Wlin = (const float*)d_in[9];
    const float* blin = (const float*)d_in[10];
    float* out = (float*)d_out;

    int N = in_sizes[0] / DIM;
    int E = in_sizes[1] / 2;
    int G = out_size / DIM;
    const int* srcv = edge;
    const int* dstv = edge + E;
    int B = (N + NB - 1) >> NB_SHIFT;

    char* ws = (char*)d_ws;
    auto alloc = [&](size_t bytes) {
        char* p = ws;
        ws += (bytes + 255) & ~(size_t)255;
        return p;
    };
    int*   bucketCnt    = (int*)alloc((size_t)B * 4);
    int*   bucketOff    = (int*)alloc((size_t)(B + 1) * 4);
    int*   bucketCursor = (int*)alloc((size_t)B * 4);
    int*   pairs        = (int*)alloc((size_t)E * 4);
    int*   row_ptr      = (int*)alloc(((size_t)N + 1) * 4);
    int*   colv         = (int*)alloc((size_t)E * 4);
    float* dinv         = (float*)alloc((size_t)N * 4);
    float* Xs           = (float*)alloc((size_t)N * DIM * 4);
    float* buf0         = (float*)alloc((size_t)N * DIM * 4);
    float* buf1         = (float*)alloc((size_t)N * DIM * 4);
    float* sums         = (float*)alloc((size_t)G * DIM * 4);

    hipMemsetAsync(bucketCnt, 0, (size_t)B * 4, stream);
    hipMemsetAsync(sums, 0, (size_t)G * DIM * 4, stream);

    // Bucketed CSR build (once; shared by all 3 layers); k_buildCSR also emits Xs = x*dinv
    k_binA<<<512, 256, 0, stream>>>(dstv, E, B, bucketCnt);
    k_scanB<<<1, 256, 0, stream>>>(bucketCnt, B, E, N, bucketOff, bucketCursor, row_ptr);
    k_binB<<<(E + TILE - 1) / TILE, 256, 0, stream>>>(srcv, dstv, E, B, bucketCursor, pairs);
    k_buildCSR<<<B, 256, 0, stream>>>(pairs, bucketOff, N, row_ptr, colv, dinv, x, Xs);

    int layerBlocks = (N + 4 * NPW - 1) / (4 * NPW);

    k_layer<true, true><<<layerBlocks, 256, 0, stream>>>(Xs, row_ptr, colv, dinv, W1, b1, buf0, N);
    k_layer<true, true><<<layerBlocks, 256, 0, stream>>>(buf0, row_ptr, colv, dinv, W2, b2, buf1, N);
    k_layer<false, false><<<layerBlocks, 256, 0, stream>>>(buf1, row_ptr, colv, dinv, W3, b3, buf0, N);

    // Global mean pool + linear head
    int chunk = 64;
    int poolBlocks = (N + 4 * chunk - 1) / (4 * chunk);
    k_pool<<<poolBlocks, 256, 0, stream>>>(buf0, batch, N, sums, chunk);
    k_final<<<G, 64, 0, stream>>>(sums, batch, N, Wlin, blin, out);
}

// Round 7
// 1088.584 us; speedup vs baseline: 1.6660x; 1.6660x over previous
//
#include <hip/hip_runtime.h>

#define DIM 64
#define NPW 8         // nodes per wave in k_layer (2 batches of 4)
#define NB_SHIFT 8    // 256 nodes per bucket
#define NB 256
#define BMAX 1024     // max buckets supported (N <= 262144)
#define TILE 4096     // edges per binB block
#define EPT 16        // TILE / 256

// ---------------- bucketed CSR build ----------------

__global__ __launch_bounds__(256) void k_binA(const int* __restrict__ dst, int E, int B,
                                              int* __restrict__ bucketCnt) {
    __shared__ int cntL[BMAX];
    int t = threadIdx.x;
    for (int j = t; j < B; j += 256) cntL[j] = 0;
    __syncthreads();
    int stride = gridDim.x * 256;
    for (int i = blockIdx.x * 256 + t; i < E; i += stride)
        atomicAdd(&cntL[dst[i] >> NB_SHIFT], 1);
    __syncthreads();
    for (int j = t; j < B; j += 256)
        if (cntL[j]) atomicAdd(&bucketCnt[j], cntL[j]);
}

__global__ __launch_bounds__(256) void k_scanB(const int* __restrict__ bucketCnt, int B, int E, int N,
                                               int* __restrict__ bucketOff,
                                               int* __restrict__ bucketCursor,
                                               int* __restrict__ row_ptr) {
    __shared__ int sdata[256];
    int t = threadIdx.x;
    int i0 = 2 * t, i1 = 2 * t + 1;
    int a0 = (i0 < B) ? bucketCnt[i0] : 0;
    int a1 = (i1 < B) ? bucketCnt[i1] : 0;
    int s = a0 + a1;
    sdata[t] = s;
    __syncthreads();
    for (int off = 1; off < 256; off <<= 1) {
        int tmp = (t >= off) ? sdata[t - off] : 0;
        __syncthreads();
        if (t >= off) sdata[t] += tmp;
        __syncthreads();
    }
    int excl = sdata[t] - s;
    if (i0 <= B) { bucketOff[i0] = excl; if (i0 < B) bucketCursor[i0] = excl; }
    int o1 = excl + a0;
    if (i1 <= B) { bucketOff[i1] = o1; if (i1 < B) bucketCursor[i1] = o1; }
    if (t == 0) row_ptr[N] = E;
}

__global__ __launch_bounds__(256) void k_binB(const int* __restrict__ src, const int* __restrict__ dst,
                                              int E, int B, int* __restrict__ bucketCursor,
                                              int* __restrict__ pairs) {
    __shared__ int cntL[BMAX];
    __shared__ int baseL[BMAX];
    int t = threadIdx.x;
    for (int j = t; j < B; j += 256) cntL[j] = 0;
    __syncthreads();
    int tile0 = blockIdx.x * TILE;
    int s_[EPT], d_[EPT], o_[EPT];
#pragma unroll
    for (int j = 0; j < EPT; ++j) {
        int i = tile0 + j * 256 + t;
        if (i < E) {
            s_[j] = src[i];
            d_[j] = dst[i];
            o_[j] = atomicAdd(&cntL[d_[j] >> NB_SHIFT], 1);
        } else {
            d_[j] = -1;
        }
    }
    __syncthreads();
    for (int j = t; j < B; j += 256)
        if (cntL[j]) baseL[j] = atomicAdd(&bucketCursor[j], cntL[j]);
    __syncthreads();
#pragma unroll
    for (int j = 0; j < EPT; ++j) {
        if (d_[j] >= 0) {
            int b = d_[j] >> NB_SHIFT;
            pairs[baseL[b] + o_[j]] = ((d_[j] & (NB - 1)) << 17) | s_[j];
        }
    }
}

__global__ __launch_bounds__(256) void k_buildCSR(const int* __restrict__ pairs,
                                                  const int* __restrict__ bucketOff,
                                                  int N, int* __restrict__ row_ptr,
                                                  int* __restrict__ col,
                                                  float* __restrict__ dinv,
                                                  const float* __restrict__ x,
                                                  float* __restrict__ Xs) {
    __shared__ int cntL[NB];
    __shared__ int sdata[NB];
    __shared__ int curL[NB];
    __shared__ float dinvL[NB];
    int t = threadIdx.x;
    int b = blockIdx.x;
    int nodeBase = b << NB_SHIFT;
    int nNodes = N - nodeBase; if (nNodes > NB) nNodes = NB;
    int e0 = bucketOff[b], e1 = bucketOff[b + 1];
    cntL[t] = 0;
    __syncthreads();
    for (int i = e0 + t; i < e1; i += 256)
        atomicAdd(&cntL[pairs[i] >> 17], 1);
    __syncthreads();
    int c = cntL[t];
    sdata[t] = c;
    __syncthreads();
    for (int off = 1; off < 256; off <<= 1) {
        int tmp = (t >= off) ? sdata[t - off] : 0;
        __syncthreads();
        if (t >= off) sdata[t] += tmp;
        __syncthreads();
    }
    int excl = sdata[t] - c;
    float dv = rsqrtf((float)(c + 1));
    if (t < nNodes) {
        row_ptr[nodeBase + t] = e0 + excl;
        dinv[nodeBase + t] = dv;
    }
    dinvL[t] = dv;
    curL[t] = excl;
    __syncthreads();
    for (int i = e0 + t; i < e1; i += 256) {
        int p = pairs[i];
        int l = p >> 17;
        int slot = atomicAdd(&curL[l], 1);
        col[e0 + slot] = p & 0x1FFFF;
    }
    int total = nNodes * DIM;
    int base64 = nodeBase << 6;
    for (int i = t; i < total; i += 256)
        Xs[base64 + i] = x[base64 + i] * dinvL[i >> 6];
}

// ---------------- fused layer ----------------
// z_j = In[v_j] + sum_{u in CSR[v_j]} In[u]   (quad-group float4 gather, 4 loads in flight)
// h_j = dinv[v_j]*(z_j @ W) + b ; Out = SCALE_OUT ? dinv*act(h) : act(h)
// Epilogue batches 4 nodes (z_j and dv_j staged to LDS) so each WL4 b128 read is
// reused 4x (16 -> 4 reads/node).  NO dynamically-indexed register arrays (round-6
// spill lesson) and __launch_bounds__(256,4) for VGPR headroom.
template <bool RELU, bool SCALE_OUT>
__global__ __launch_bounds__(256, 4) void k_layer(const float* __restrict__ In,
                                                  const int* __restrict__ row_ptr,
                                                  const int* __restrict__ col,
                                                  const float* __restrict__ dinv,
                                                  const float* __restrict__ W,
                                                  const float* __restrict__ bias,
                                                  float* __restrict__ Out, int N) {
    __shared__ float WLs[DIM * DIM];   // 16 KB: WLs[k16*256 + col*4 + j] = W[4*k16+j][col]
    __shared__ float4 zS[4 * 64];      // 4 KB: per wave, 4 nodes x 16 chunks
    __shared__ float dvS[4 * 4];       // per wave, 4 node dinv values
    int t = threadIdx.x;
    int lane = t & 63;
    int wave = t >> 6;
    int g = lane >> 4;    // quad group 0..3
    int gl = lane & 15;   // float4 index within a row

    for (int k = wave; k < DIM; k += 4)
        WLs[(k >> 2) * 256 + lane * 4 + (k & 3)] = W[k * DIM + lane];
    __syncthreads();
    const float4* WL4 = (const float4*)WLs;

    float blane = bias[lane];
    const float4* InR = (const float4*)In;

    int v0 = (blockIdx.x * 4 + wave) * NPW;
    for (int rb = 0; rb < NPW / 4; ++rb) {
        int vb = v0 + rb * 4;
        if (vb >= N) return;
        // ---- gather phase: 4 nodes, z (and dv) staged to LDS ----
        for (int j = 0; j < 4; ++j) {
            int v = vb + j;
            int vc = (v < N) ? v : (N - 1);
            int e0 = row_ptr[vc];
            int e1 = row_ptr[vc + 1];
            if (lane == 0) dvS[wave * 4 + j] = dinv[vc];
            int d1 = e1 - e0 + 1;  // neighbors + self
            float4 acc0 = make_float4(0.f, 0.f, 0.f, 0.f);
            float4 acc1 = make_float4(0.f, 0.f, 0.f, 0.f);
            float4 acc2 = make_float4(0.f, 0.f, 0.f, 0.f);
            float4 acc3 = make_float4(0.f, 0.f, 0.f, 0.f);
            int base = 0;
            while (base < d1) {
                int m = d1 - base; if (m > 64) m = 64;
                int slot = base + lane;
                int u = vc;
                if (slot > 0 && slot < d1) u = col[e0 + slot - 1];
                int nfull = m >> 2;
                int q = 0;
                for (; q + 4 <= nfull; q += 4) {
                    int u0 = __shfl(u, (q + 0) * 4 + g, 64);
                    int u1 = __shfl(u, (q + 1) * 4 + g, 64);
                    int u2 = __shfl(u, (q + 2) * 4 + g, 64);
                    int u3 = __shfl(u, (q + 3) * 4 + g, 64);
                    float4 a0 = InR[u0 * 16 + gl];
                    float4 a1 = InR[u1 * 16 + gl];
                    float4 a2 = InR[u2 * 16 + gl];
                    float4 a3 = InR[u3 * 16 + gl];
                    acc0.x += a0.x; acc0.y += a0.y; acc0.z += a0.z; acc0.w += a0.w;
                    acc1.x += a1.x; acc1.y += a1.y; acc1.z += a1.z; acc1.w += a1.w;
                    acc2.x += a2.x; acc2.y += a2.y; acc2.z += a2.z; acc2.w += a2.w;
                    acc3.x += a3.x; acc3.y += a3.y; acc3.z += a3.z; acc3.w += a3.w;
                }
                for (; q + 2 <= nfull; q += 2) {
                    int u0 = __shfl(u, (q + 0) * 4 + g, 64);
                    int u1 = __shfl(u, (q + 1) * 4 + g, 64);
                    float4 a0 = InR[u0 * 16 + gl];
                    float4 a1 = InR[u1 * 16 + gl];
                    acc0.x += a0.x; acc0.y += a0.y; acc0.z += a0.z; acc0.w += a0.w;
                    acc1.x += a1.x; acc1.y += a1.y; acc1.z += a1.z; acc1.w += a1.w;
                }
                for (; q < nfull; ++q) {
                    int u0 = __shfl(u, q * 4 + g, 64);
                    float4 a0 = InR[u0 * 16 + gl];
                    acc0.x += a0.x; acc0.y += a0.y; acc0.z += a0.z; acc0.w += a0.w;
                }
                if (m & 3) {
                    int sidx = nfull * 4 + g;
                    bool ok = sidx < m;
                    int uu = __shfl(u, ok ? sidx : 0, 64);
                    float4 a0 = InR[uu * 16 + gl];
                    if (ok) { acc0.x += a0.x; acc0.y += a0.y; acc0.z += a0.z; acc0.w += a0.w; }
                }
                base += m;
            }
            float4 z;
            z.x = (acc0.x + acc1.x) + (acc2.x + acc3.x);
            z.y = (acc0.y + acc1.y) + (acc2.y + acc3.y);
            z.z = (acc0.z + acc1.z) + (acc2.z + acc3.z);
            z.w = (acc0.w + acc1.w) + (acc2.w + acc3.w);
            z.x += __shfl_xor(z.x, 16, 64); z.y += __shfl_xor(z.y, 16, 64);
            z.z += __shfl_xor(z.z, 16, 64); z.w += __shfl_xor(z.w, 16, 64);
            z.x += __shfl_xor(z.x, 32, 64); z.y += __shfl_xor(z.y, 32, 64);
            z.z += __shfl_xor(z.z, 32, 64); z.w += __shfl_xor(z.w, 32, 64);
            if (g == 0) zS[wave * 64 + j * 16 + gl] = z;  // intra-wave, no barrier
        }
        // ---- batched epilogue: one W pass for 4 nodes ----
        float r0 = 0.f, r1 = 0.f, r2 = 0.f, r3 = 0.f;
#pragma unroll
        for (int k16 = 0; k16 < 16; ++k16) {
            float4 wv = WL4[k16 * 64 + lane];
            float4 z0 = zS[wave * 64 + 0 * 16 + k16];  // broadcast reads
            float4 z1 = zS[wave * 64 + 1 * 16 + k16];
            float4 z2 = zS[wave * 64 + 2 * 16 + k16];
            float4 z3 = zS[wave * 64 + 3 * 16 + k16];
            r0 = fmaf(z0.x, wv.x, fmaf(z0.y, wv.y, fmaf(z0.z, wv.z, fmaf(z0.w, wv.w, r0))));
            r1 = fmaf(z1.x, wv.x, fmaf(z1.y, wv.y, fmaf(z1.z, wv.z, fmaf(z1.w, wv.w, r1))));
            r2 = fmaf(z2.x, wv.x, fmaf(z2.y, wv.y, fmaf(z2.z, wv.z, fmaf(z2.w, wv.w, r2))));
            r3 = fmaf(z3.x, wv.x, fmaf(z3.y, wv.y, fmaf(z3.z, wv.z, fmaf(z3.w, wv.w, r3))));
        }
        {
            float dv0 = dvS[wave * 4 + 0];
            float h = fmaf(dv0, r0, blane);
            if (RELU) h = fmaxf(h, 0.f);
            if (SCALE_OUT) h *= dv0;
            if (vb + 0 < N) Out[(vb + 0) * DIM + lane] = h;
        }
        {
            float dv1 = dvS[wave * 4 + 1];
            float h = fmaf(dv1, r1, blane);
            if (RELU) h = fmaxf(h, 0.f);
            if (SCALE_OUT) h *= dv1;
            if (vb + 1 < N) Out[(vb + 1) * DIM + lane] = h;
        }
        {
            float dv2 = dvS[wave * 4 + 2];
            float h = fmaf(dv2, r2, blane);
            if (RELU) h = fmaxf(h, 0.f);
            if (SCALE_OUT) h *= dv2;
            if (vb + 2 < N) Out[(vb + 2) * DIM + lane] = h;
        }
        {
            float dv3 = dvS[wave * 4 + 3];
            float h = fmaf(dv3, r3, blane);
            if (RELU) h = fmaxf(h, 0.f);
            if (SCALE_OUT) h *= dv3;
            if (vb + 3 < N) Out[(vb + 3) * DIM + lane] = h;
        }
    }
}

// ---------------- pooling + head ----------------

__global__ __launch_bounds__(256) void k_pool(const float* __restrict__ H, const int* __restrict__ batch,
                                              int N, float* __restrict__ sums, int chunk) {
    int t = threadIdx.x;
    int lane = t & 63;
    int start = (blockIdx.x * 4 + (t >> 6)) * chunk;
    int end = start + chunk; if (end > N) end = N;
    if (start >= end) return;
    float acc = 0.f;
    int cur = batch[start];
    for (int i = start; i < end; ++i) {
        int b = batch[i];
        if (b != cur) {
            atomicAdd(&sums[cur * DIM + lane], acc);
            acc = 0.f; cur = b;
        }
        acc += H[i * DIM + lane];
    }
    atomicAdd(&sums[cur * DIM + lane], acc);
}

__global__ __launch_bounds__(64) void k_final(const float* __restrict__ sums,
                                              const int* __restrict__ batch, int N,
                                              const float* __restrict__ Wlin,
                                              const float* __restrict__ blin,
                                              float* __restrict__ out) {
    int g = blockIdx.x;
    int j = threadIdx.x;
    int lo = 0, hi = N;
    while (lo < hi) { int mid = (lo + hi) >> 1; if (batch[mid] < g) lo = mid + 1; else hi = mid; }
    int c0 = lo;
    lo = 0; hi = N;
    int g1 = g + 1;
    while (lo < hi) { int mid = (lo + hi) >> 1; if (batch[mid] < g1) lo = mid + 1; else hi = mid; }
    int c1 = lo;
    int c = c1 - c0; if (c < 1) c = 1;
    float invc = 1.0f / (float)c;
    float acc = 0.f;
#pragma unroll
    for (int k = 0; k < DIM; ++k)
        acc = fmaf(sums[g * DIM + k] * invc, Wlin[k * DIM + j], acc);
    out[g * DIM + j] = acc + blin[j];
}

// ---------------- launch ----------------

extern "C" void kernel_launch(void* const* d_in, const int* in_sizes, int n_in,
                              void* d_out, int out_size, void* d_ws, size_t ws_size,
                              hipStream_t stream) {
    const float* x    = (const float*)d_in[0];
    const int*   edge = (const int*)d_in[1];
    const int*   batch= (const int*)d_in[2];
    const float* W1 = (const float*)d_in[3];
    const float* b1 = (const float*)d_in[4];
    const float* W2 = (const float*)d_in[5];
    const float* b2 = (const float*)d_in[6];
    const float* W3 = (const float*)d_in[7];
    const float* b3 = (const float*)d_in[8];
    const float* Wlin = (const float*)d_in[9];
    const float* blin = (const float*)d_in[10];
    float* out = (float*)d_out;

    int N = in_sizes[0] / DIM;
    int E = in_sizes[1] / 2;
    int G = out_size / DIM;
    const int* srcv = edge;
    const int* dstv = edge + E;
    int B = (N + NB - 1) >> NB_SHIFT;

    char* ws = (char*)d_ws;
    auto alloc = [&](size_t bytes) {
        char* p = ws;
        ws += (bytes + 255) & ~(size_t)255;
        return p;
    };
    int*   bucketCnt    = (int*)alloc((size_t)B * 4);
    int*   bucketOff    = (int*)alloc((size_t)(B + 1) * 4);
    int*   bucketCursor = (int*)alloc((size_t)B * 4);
    int*   pairs        = (int*)alloc((size_t)E * 4);
    int*   row_ptr      = (int*)alloc(((size_t)N + 1) * 4);
    int*   colv         = (int*)alloc((size_t)E * 4);
    float* dinv         = (float*)alloc((size_t)N * 4);
    float* Xs           = (float*)alloc((size_t)N * DIM * 4);
    float* buf0         = (float*)alloc((size_t)N * DIM * 4);
    float* buf1         = (float*)alloc((size_t)N * DIM * 4);
    float* sums         = (float*)alloc((size_t)G * DIM * 4);

    hipMemsetAsync(bucketCnt, 0, (size_t)B * 4, stream);
    hipMemsetAsync(sums, 0, (size_t)G * DIM * 4, stream);

    k_binA<<<512, 256, 0, stream>>>(dstv, E, B, bucketCnt);
    k_scanB<<<1, 256, 0, stream>>>(bucketCnt, B, E, N, bucketOff, bucketCursor, row_ptr);
    k_binB<<<(E + TILE - 1) / TILE, 256, 0, stream>>>(srcv, dstv, E, B, bucketCursor, pairs);
    k_buildCSR<<<B, 256, 0, stream>>>(pairs, bucketOff, N, row_ptr, colv, dinv, x, Xs);

    int layerBlocks = (N + 4 * NPW - 1) / (4 * NPW);

    k_layer<true, true><<<layerBlocks, 256, 0, stream>>>(Xs, row_ptr, colv, dinv, W1, b1, buf0, N);
    k_layer<true, true><<<layerBlocks, 256, 0, stream>>>(buf0, row_ptr, colv, dinv, W2, b2, buf1, N);
    k_layer<false, false><<<layerBlocks, 256, 0, stream>>>(buf1, row_ptr, colv, dinv, W3, b3, buf0, N);

    int chunk = 64;
    int poolBlocks = (N + 4 * chunk - 1) / (4 * chunk);
    k_pool<<<poolBlocks, 256, 0, stream>>>(buf0, batch, N, sums, chunk);
    k_final<<<G, 64, 0, stream>>>(sums, batch, N, Wlin, blin, out);
}

// Round 8
// 1084.070 us; speedup vs baseline: 1.6729x; 1.0042x over previous
//
#include <hip/hip_runtime.h>

#define DIM 64
#define NPW 8         // nodes per wave in k_layer (2 batches of 4)
#define NB_SHIFT 8    // 256 nodes per bucket
#define NB 256
#define BMAX 1024     // max buckets supported (N <= 262144)
#define TILE 4096     // edges per binB block
#define EPT 16        // TILE / 256

// ---------------- bucketed CSR build ----------------

__global__ __launch_bounds__(256) void k_binA(const int* __restrict__ dst, int E, int B,
                                              int* __restrict__ bucketCnt) {
    __shared__ int cntL[BMAX];
    int t = threadIdx.x;
    for (int j = t; j < B; j += 256) cntL[j] = 0;
    __syncthreads();
    int stride = gridDim.x * 256;
    for (int i = blockIdx.x * 256 + t; i < E; i += stride)
        atomicAdd(&cntL[dst[i] >> NB_SHIFT], 1);
    __syncthreads();
    for (int j = t; j < B; j += 256)
        if (cntL[j]) atomicAdd(&bucketCnt[j], cntL[j]);
}

__global__ __launch_bounds__(256) void k_scanB(const int* __restrict__ bucketCnt, int B, int E, int N,
                                               int* __restrict__ bucketOff,
                                               int* __restrict__ bucketCursor,
                                               int* __restrict__ row_ptr) {
    __shared__ int sdata[256];
    int t = threadIdx.x;
    int i0 = 2 * t, i1 = 2 * t + 1;
    int a0 = (i0 < B) ? bucketCnt[i0] : 0;
    int a1 = (i1 < B) ? bucketCnt[i1] : 0;
    int s = a0 + a1;
    sdata[t] = s;
    __syncthreads();
    for (int off = 1; off < 256; off <<= 1) {
        int tmp = (t >= off) ? sdata[t - off] : 0;
        __syncthreads();
        if (t >= off) sdata[t] += tmp;
        __syncthreads();
    }
    int excl = sdata[t] - s;
    if (i0 <= B) { bucketOff[i0] = excl; if (i0 < B) bucketCursor[i0] = excl; }
    int o1 = excl + a0;
    if (i1 <= B) { bucketOff[i1] = o1; if (i1 < B) bucketCursor[i1] = o1; }
    if (t == 0) row_ptr[N] = E;
}

__global__ __launch_bounds__(256) void k_binB(const int* __restrict__ src, const int* __restrict__ dst,
                                              int E, int B, int* __restrict__ bucketCursor,
                                              int* __restrict__ pairs) {
    __shared__ int cntL[BMAX];
    __shared__ int baseL[BMAX];
    int t = threadIdx.x;
    for (int j = t; j < B; j += 256) cntL[j] = 0;
    __syncthreads();
    int tile0 = blockIdx.x * TILE;
    int s_[EPT], d_[EPT], o_[EPT];
#pragma unroll
    for (int j = 0; j < EPT; ++j) {
        int i = tile0 + j * 256 + t;
        if (i < E) {
            s_[j] = src[i];
            d_[j] = dst[i];
            o_[j] = atomicAdd(&cntL[d_[j] >> NB_SHIFT], 1);
        } else {
            d_[j] = -1;
        }
    }
    __syncthreads();
    for (int j = t; j < B; j += 256)
        if (cntL[j]) baseL[j] = atomicAdd(&bucketCursor[j], cntL[j]);
    __syncthreads();
#pragma unroll
    for (int j = 0; j < EPT; ++j) {
        if (d_[j] >= 0) {
            int b = d_[j] >> NB_SHIFT;
            pairs[baseL[b] + o_[j]] = ((d_[j] & (NB - 1)) << 17) | s_[j];
        }
    }
}

__global__ __launch_bounds__(256) void k_buildCSR(const int* __restrict__ pairs,
                                                  const int* __restrict__ bucketOff,
                                                  int N, int* __restrict__ row_ptr,
                                                  int* __restrict__ col,
                                                  float* __restrict__ dinv,
                                                  const float* __restrict__ x,
                                                  float* __restrict__ Xs) {
    __shared__ int cntL[NB];
    __shared__ int sdata[NB];
    __shared__ int curL[NB];
    __shared__ float dinvL[NB];
    int t = threadIdx.x;
    int b = blockIdx.x;
    int nodeBase = b << NB_SHIFT;
    int nNodes = N - nodeBase; if (nNodes > NB) nNodes = NB;
    int e0 = bucketOff[b], e1 = bucketOff[b + 1];
    cntL[t] = 0;
    __syncthreads();
    for (int i = e0 + t; i < e1; i += 256)
        atomicAdd(&cntL[pairs[i] >> 17], 1);
    __syncthreads();
    int c = cntL[t];
    sdata[t] = c;
    __syncthreads();
    for (int off = 1; off < 256; off <<= 1) {
        int tmp = (t >= off) ? sdata[t - off] : 0;
        __syncthreads();
        if (t >= off) sdata[t] += tmp;
        __syncthreads();
    }
    int excl = sdata[t] - c;
    float dv = rsqrtf((float)(c + 1));
    if (t < nNodes) {
        row_ptr[nodeBase + t] = e0 + excl;
        dinv[nodeBase + t] = dv;
    }
    dinvL[t] = dv;
    curL[t] = excl;
    __syncthreads();
    for (int i = e0 + t; i < e1; i += 256) {
        int p = pairs[i];
        int l = p >> 17;
        int slot = atomicAdd(&curL[l], 1);
        col[e0 + slot] = p & 0x1FFFF;
    }
    int total = nNodes * DIM;
    int base64 = nodeBase << 6;
    for (int i = t; i < total; i += 256)
        Xs[base64 + i] = x[base64 + i] * dinvL[i >> 6];
}

// ---------------- fused layer ----------------
// z_j = In[v_j] + sum_{u in CSR[v_j]} In[u]   (quad-group float4 gather, 4 loads in flight)
// h_j = dinv[v_j]*(z_j @ W) + b ; Out = SCALE_OUT ? dinv*act(h) : act(h)
// Epilogue batches 4 nodes (z_j, dv_j staged in LDS) -> each WL4 b128 read reused 4x.
// CRITICAL (round-7 lesson): the 4-gather j-loop must NOT be unrolled -- unrolling
// lets the scheduler interleave 4 gather bodies (4x16 acc VGPRs live) and spill.
template <bool RELU, bool SCALE_OUT>
__global__ __launch_bounds__(256, 4) void k_layer(const float* __restrict__ In,
                                                  const int* __restrict__ row_ptr,
                                                  const int* __restrict__ col,
                                                  const float* __restrict__ dinv,
                                                  const float* __restrict__ W,
                                                  const float* __restrict__ bias,
                                                  float* __restrict__ Out, int N) {
    __shared__ float WLs[DIM * DIM];   // 16 KB: WLs[k16*256 + col*4 + j] = W[4*k16+j][col]
    __shared__ float4 zS[4 * 64];      // 4 KB: per wave, 4 nodes x 16 chunks
    __shared__ float dvS[4 * 4];       // per wave, 4 node dinv values
    int t = threadIdx.x;
    int lane = t & 63;
    int wave = t >> 6;
    int g = lane >> 4;    // quad group 0..3
    int gl = lane & 15;   // float4 index within a row

    for (int k = wave; k < DIM; k += 4)
        WLs[(k >> 2) * 256 + lane * 4 + (k & 3)] = W[k * DIM + lane];
    __syncthreads();
    const float4* WL4 = (const float4*)WLs;

    float blane = bias[lane];
    const float4* InR = (const float4*)In;

    int v0 = (blockIdx.x * 4 + wave) * NPW;
#pragma unroll 1
    for (int rb = 0; rb < NPW / 4; ++rb) {
        int vb = v0 + rb * 4;
        if (vb >= N) return;
        // ---- gather phase: 4 nodes sequentially (DO NOT UNROLL), z+dv staged to LDS ----
#pragma unroll 1
        for (int j = 0; j < 4; ++j) {
            int v = vb + j;
            int vc = (v < N) ? v : (N - 1);
            int e0 = row_ptr[vc];
            int e1 = row_ptr[vc + 1];
            if (lane == 0) dvS[wave * 4 + j] = dinv[vc];
            int d1 = e1 - e0 + 1;  // neighbors + self
            float4 acc0 = make_float4(0.f, 0.f, 0.f, 0.f);
            float4 acc1 = make_float4(0.f, 0.f, 0.f, 0.f);
            float4 acc2 = make_float4(0.f, 0.f, 0.f, 0.f);
            float4 acc3 = make_float4(0.f, 0.f, 0.f, 0.f);
            int base = 0;
            while (base < d1) {
                int m = d1 - base; if (m > 64) m = 64;
                int slot = base + lane;
                int u = vc;
                if (slot > 0 && slot < d1) u = col[e0 + slot - 1];
                int nfull = m >> 2;
                int q = 0;
                for (; q + 4 <= nfull; q += 4) {
                    int u0 = __shfl(u, (q + 0) * 4 + g, 64);
                    int u1 = __shfl(u, (q + 1) * 4 + g, 64);
                    int u2 = __shfl(u, (q + 2) * 4 + g, 64);
                    int u3 = __shfl(u, (q + 3) * 4 + g, 64);
                    float4 a0 = InR[u0 * 16 + gl];
                    float4 a1 = InR[u1 * 16 + gl];
                    float4 a2 = InR[u2 * 16 + gl];
                    float4 a3 = InR[u3 * 16 + gl];
                    acc0.x += a0.x; acc0.y += a0.y; acc0.z += a0.z; acc0.w += a0.w;
                    acc1.x += a1.x; acc1.y += a1.y; acc1.z += a1.z; acc1.w += a1.w;
                    acc2.x += a2.x; acc2.y += a2.y; acc2.z += a2.z; acc2.w += a2.w;
                    acc3.x += a3.x; acc3.y += a3.y; acc3.z += a3.z; acc3.w += a3.w;
                }
                for (; q + 2 <= nfull; q += 2) {
                    int u0 = __shfl(u, (q + 0) * 4 + g, 64);
                    int u1 = __shfl(u, (q + 1) * 4 + g, 64);
                    float4 a0 = InR[u0 * 16 + gl];
                    float4 a1 = InR[u1 * 16 + gl];
                    acc0.x += a0.x; acc0.y += a0.y; acc0.z += a0.z; acc0.w += a0.w;
                    acc1.x += a1.x; acc1.y += a1.y; acc1.z += a1.z; acc1.w += a1.w;
                }
                for (; q < nfull; ++q) {
                    int u0 = __shfl(u, q * 4 + g, 64);
                    float4 a0 = InR[u0 * 16 + gl];
                    acc0.x += a0.x; acc0.y += a0.y; acc0.z += a0.z; acc0.w += a0.w;
                }
                if (m & 3) {
                    int sidx = nfull * 4 + g;
                    bool ok = sidx < m;
                    int uu = __shfl(u, ok ? sidx : 0, 64);
                    float4 a0 = InR[uu * 16 + gl];
                    if (ok) { acc0.x += a0.x; acc0.y += a0.y; acc0.z += a0.z; acc0.w += a0.w; }
                }
                base += m;
            }
            float4 z;
            z.x = (acc0.x + acc1.x) + (acc2.x + acc3.x);
            z.y = (acc0.y + acc1.y) + (acc2.y + acc3.y);
            z.z = (acc0.z + acc1.z) + (acc2.z + acc3.z);
            z.w = (acc0.w + acc1.w) + (acc2.w + acc3.w);
            z.x += __shfl_xor(z.x, 16, 64); z.y += __shfl_xor(z.y, 16, 64);
            z.z += __shfl_xor(z.z, 16, 64); z.w += __shfl_xor(z.w, 16, 64);
            z.x += __shfl_xor(z.x, 32, 64); z.y += __shfl_xor(z.y, 32, 64);
            z.z += __shfl_xor(z.z, 32, 64); z.w += __shfl_xor(z.w, 32, 64);
            if (g == 0) zS[wave * 64 + j * 16 + gl] = z;  // intra-wave, no barrier
        }
        // ---- batched epilogue: one W pass for 4 nodes ----
        float r0 = 0.f, r1 = 0.f, r2 = 0.f, r3 = 0.f;
#pragma unroll
        for (int k16 = 0; k16 < 16; ++k16) {
            float4 wv = WL4[k16 * 64 + lane];
            float4 z0 = zS[wave * 64 + 0 * 16 + k16];  // broadcast reads
            float4 z1 = zS[wave * 64 + 1 * 16 + k16];
            float4 z2 = zS[wave * 64 + 2 * 16 + k16];
            float4 z3 = zS[wave * 64 + 3 * 16 + k16];
            r0 = fmaf(z0.x, wv.x, fmaf(z0.y, wv.y, fmaf(z0.z, wv.z, fmaf(z0.w, wv.w, r0))));
            r1 = fmaf(z1.x, wv.x, fmaf(z1.y, wv.y, fmaf(z1.z, wv.z, fmaf(z1.w, wv.w, r1))));
            r2 = fmaf(z2.x, wv.x, fmaf(z2.y, wv.y, fmaf(z2.z, wv.z, fmaf(z2.w, wv.w, r2))));
            r3 = fmaf(z3.x, wv.x, fmaf(z3.y, wv.y, fmaf(z3.z, wv.z, fmaf(z3.w, wv.w, r3))));
        }
        {
            float dv0 = dvS[wave * 4 + 0];
            float h = fmaf(dv0, r0, blane);
            if (RELU) h = fmaxf(h, 0.f);
            if (SCALE_OUT) h *= dv0;
            if (vb + 0 < N) Out[(vb + 0) * DIM + lane] = h;
        }
        {
            float dv1 = dvS[wave * 4 + 1];
            float h = fmaf(dv1, r1, blane);
            if (RELU) h = fmaxf(h, 0.f);
            if (SCALE_OUT) h *= dv1;
            if (vb + 1 < N) Out[(vb + 1) * DIM + lane] = h;
        }
        {
            float dv2 = dvS[wave * 4 + 2];
            float h = fmaf(dv2, r2, blane);
            if (RELU) h = fmaxf(h, 0.f);
            if (SCALE_OUT) h *= dv2;
            if (vb + 2 < N) Out[(vb + 2) * DIM + lane] = h;
        }
        {
            float dv3 = dvS[wave * 4 + 3];
            float h = fmaf(dv3, r3, blane);
            if (RELU) h = fmaxf(h, 0.f);
            if (SCALE_OUT) h *= dv3;
            if (vb + 3 < N) Out[(vb + 3) * DIM + lane] = h;
        }
    }
}

// ---------------- pooling + head ----------------

__global__ __launch_bounds__(256) void k_pool(const float* __restrict__ H, const int* __restrict__ batch,
                                              int N, float* __restrict__ sums, int chunk) {
    int t = threadIdx.x;
    int lane = t & 63;
    int start = (blockIdx.x * 4 + (t >> 6)) * chunk;
    int end = start + chunk; if (end > N) end = N;
    if (start >= end) return;
    float acc = 0.f;
    int cur = batch[start];
    for (int i = start; i < end; ++i) {
        int b = batch[i];
        if (b != cur) {
            atomicAdd(&sums[cur * DIM + lane], acc);
            acc = 0.f; cur = b;
        }
        acc += H[i * DIM + lane];
    }
    atomicAdd(&sums[cur * DIM + lane], acc);
}

__global__ __launch_bounds__(64) void k_final(const float* __restrict__ sums,
                                              const int* __restrict__ batch, int N,
                                              const float* __restrict__ Wlin,
                                              const float* __restrict__ blin,
                                              float* __restrict__ out) {
    int g = blockIdx.x;
    int j = threadIdx.x;
    int lo = 0, hi = N;
    while (lo < hi) { int mid = (lo + hi) >> 1; if (batch[mid] < g) lo = mid + 1; else hi = mid; }
    int c0 = lo;
    lo = 0; hi = N;
    int g1 = g + 1;
    while (lo < hi) { int mid = (lo + hi) >> 1; if (batch[mid] < g1) lo = mid + 1; else hi = mid; }
    int c1 = lo;
    int c = c1 - c0; if (c < 1) c = 1;
    float invc = 1.0f / (float)c;
    float acc = 0.f;
#pragma unroll
    for (int k = 0; k < DIM; ++k)
        acc = fmaf(sums[g * DIM + k] * invc, Wlin[k * DIM + j], acc);
    out[g * DIM + j] = acc + blin[j];
}

// ---------------- launch ----------------

extern "C" void kernel_launch(void* const* d_in, const int* in_sizes, int n_in,
                              void* d_out, int out_size, void* d_ws, size_t ws_size,
                              hipStream_t stream) {
    const float* x    = (const float*)d_in[0];
    const int*   edge = (const int*)d_in[1];
    const int*   batch= (const int*)d_in[2];
    const float* W1 = (const float*)d_in[3];
    const float* b1 = (const float*)d_in[4];
    const float* W2 = (const float*)d_in[5];
    const float* b2 = (const float*)d_in[6];
    const float* W3 = (const float*)d_in[7];
    const float* b3 = (const float*)d_in[8];
    const float* Wlin = (const float*)d_in[9];
    const float* blin = (const float*)d_in[10];
    float* out = (float*)d_out;

    int N = in_sizes[0] / DIM;
    int E = in_sizes[1] / 2;
    int G = out_size / DIM;
    const int* srcv = edge;
    const int* dstv = edge + E;
    int B = (N + NB - 1) >> NB_SHIFT;

    char* ws = (char*)d_ws;
    auto alloc = [&](size_t bytes) {
        char* p = ws;
        ws += (bytes + 255) & ~(size_t)255;
        return p;
    };
    int*   bucketCnt    = (int*)alloc((size_t)B * 4);
    int*   bucketOff    = (int*)alloc((size_t)(B + 1) * 4);
    int*   bucketCursor = (int*)alloc((size_t)B * 4);
    int*   pairs        = (int*)alloc((size_t)E * 4);
    int*   row_ptr      = (int*)alloc(((size_t)N + 1) * 4);
    int*   colv         = (int*)alloc((size_t)E * 4);
    float* dinv         = (float*)alloc((size_t)N * 4);
    float* Xs           = (float*)alloc((size_t)N * DIM * 4);
    float* buf0         = (float*)alloc((size_t)N * DIM * 4);
    float* buf1         = (float*)alloc((size_t)N * DIM * 4);
    float* sums         = (float*)alloc((size_t)G * DIM * 4);

    hipMemsetAsync(bucketCnt, 0, (size_t)B * 4, stream);
    hipMemsetAsync(sums, 0, (size_t)G * DIM * 4, stream);

    k_binA<<<512, 256, 0, stream>>>(dstv, E, B, bucketCnt);
    k_scanB<<<1, 256, 0, stream>>>(bucketCnt, B, E, N, bucketOff, bucketCursor, row_ptr);
    k_binB<<<(E + TILE - 1) / TILE, 256, 0, stream>>>(srcv, dstv, E, B, bucketCursor, pairs);
    k_buildCSR<<<B, 256, 0, stream>>>(pairs, bucketOff, N, row_ptr, colv, dinv, x, Xs);

    int layerBlocks = (N + 4 * NPW - 1) / (4 * NPW);

    k_layer<true, true><<<layerBlocks, 256, 0, stream>>>(Xs, row_ptr, colv, dinv, W1, b1, buf0, N);
    k_layer<true, true><<<layerBlocks, 256, 0, stream>>>(buf0, row_ptr, colv, dinv, W2, b2, buf1, N);
    k_layer<false, false><<<layerBlocks, 256, 0, stream>>>(buf1, row_ptr, colv, dinv, W3, b3, buf0, N);

    int chunk = 64;
    int poolBlocks = (N + 4 * chunk - 1) / (4 * chunk);
    k_pool<<<poolBlocks, 256, 0, stream>>>(buf0, batch, N, sums, chunk);
    k_final<<<G, 64, 0, stream>>>(sums, batch, N, Wlin, blin, out);
}

// Round 9
// 413.525 us; speedup vs baseline: 4.3856x; 2.6215x over previous
//
#include <hip/hip_runtime.h>

#define DIM 64
#define NPW 8         // nodes per wave in k_layer
#define NB_SHIFT 8    // 256 nodes per bucket
#define NB 256
#define BMAX 1024     // max buckets supported (N <= 262144)
#define TILE 4096     // edges per binB block
#define EPT 16        // TILE / 256

// ---------------- bucketed CSR build ----------------

__global__ __launch_bounds__(256) void k_binA(const int* __restrict__ dst, int E, int B,
                                              int* __restrict__ bucketCnt) {
    __shared__ int cntL[BMAX];
    int t = threadIdx.x;
    for (int j = t; j < B; j += 256) cntL[j] = 0;
    __syncthreads();
    int stride = gridDim.x * 256;
    for (int i = blockIdx.x * 256 + t; i < E; i += stride)
        atomicAdd(&cntL[dst[i] >> NB_SHIFT], 1);
    __syncthreads();
    for (int j = t; j < B; j += 256)
        if (cntL[j]) atomicAdd(&bucketCnt[j], cntL[j]);
}

__global__ __launch_bounds__(256) void k_scanB(const int* __restrict__ bucketCnt, int B, int E, int N,
                                               int* __restrict__ bucketOff,
                                               int* __restrict__ bucketCursor,
                                               int* __restrict__ row_ptr) {
    __shared__ int sdata[256];
    int t = threadIdx.x;
    int i0 = 2 * t, i1 = 2 * t + 1;
    int a0 = (i0 < B) ? bucketCnt[i0] : 0;
    int a1 = (i1 < B) ? bucketCnt[i1] : 0;
    int s = a0 + a1;
    sdata[t] = s;
    __syncthreads();
    for (int off = 1; off < 256; off <<= 1) {
        int tmp = (t >= off) ? sdata[t - off] : 0;
        __syncthreads();
        if (t >= off) sdata[t] += tmp;
        __syncthreads();
    }
    int excl = sdata[t] - s;
    if (i0 <= B) { bucketOff[i0] = excl; if (i0 < B) bucketCursor[i0] = excl; }
    int o1 = excl + a0;
    if (i1 <= B) { bucketOff[i1] = o1; if (i1 < B) bucketCursor[i1] = o1; }
    if (t == 0) row_ptr[N] = E;
}

__global__ __launch_bounds__(256) void k_binB(const int* __restrict__ src, const int* __restrict__ dst,
                                              int E, int B, int* __restrict__ bucketCursor,
                                              int* __restrict__ pairs) {
    __shared__ int cntL[BMAX];
    __shared__ int baseL[BMAX];
    int t = threadIdx.x;
    for (int j = t; j < B; j += 256) cntL[j] = 0;
    __syncthreads();
    int tile0 = blockIdx.x * TILE;
    int s_[EPT], d_[EPT], o_[EPT];
#pragma unroll
    for (int j = 0; j < EPT; ++j) {
        int i = tile0 + j * 256 + t;
        if (i < E) {
            s_[j] = src[i];
            d_[j] = dst[i];
            o_[j] = atomicAdd(&cntL[d_[j] >> NB_SHIFT], 1);
        } else {
            d_[j] = -1;
        }
    }
    __syncthreads();
    for (int j = t; j < B; j += 256)
        if (cntL[j]) baseL[j] = atomicAdd(&bucketCursor[j], cntL[j]);
    __syncthreads();
#pragma unroll
    for (int j = 0; j < EPT; ++j) {
        if (d_[j] >= 0) {
            int b = d_[j] >> NB_SHIFT;
            pairs[baseL[b] + o_[j]] = ((d_[j] & (NB - 1)) << 17) | s_[j];
        }
    }
}

__global__ __launch_bounds__(256) void k_buildCSR(const int* __restrict__ pairs,
                                                  const int* __restrict__ bucketOff,
                                                  int N, int* __restrict__ row_ptr,
                                                  int* __restrict__ col,
                                                  float* __restrict__ dinv,
                                                  const float* __restrict__ x,
                                                  float* __restrict__ Xs) {
    __shared__ int cntL[NB];
    __shared__ int sdata[NB];
    __shared__ int curL[NB];
    __shared__ float dinvL[NB];
    int t = threadIdx.x;
    int b = blockIdx.x;
    int nodeBase = b << NB_SHIFT;
    int nNodes = N - nodeBase; if (nNodes > NB) nNodes = NB;
    int e0 = bucketOff[b], e1 = bucketOff[b + 1];
    cntL[t] = 0;
    __syncthreads();
    for (int i = e0 + t; i < e1; i += 256)
        atomicAdd(&cntL[pairs[i] >> 17], 1);
    __syncthreads();
    int c = cntL[t];
    sdata[t] = c;
    __syncthreads();
    for (int off = 1; off < 256; off <<= 1) {
        int tmp = (t >= off) ? sdata[t - off] : 0;
        __syncthreads();
        if (t >= off) sdata[t] += tmp;
        __syncthreads();
    }
    int excl = sdata[t] - c;
    float dv = rsqrtf((float)(c + 1));
    if (t < nNodes) {
        row_ptr[nodeBase + t] = e0 + excl;
        dinv[nodeBase + t] = dv;
    }
    dinvL[t] = dv;
    curL[t] = excl;
    __syncthreads();
    for (int i = e0 + t; i < e1; i += 256) {
        int p = pairs[i];
        int l = p >> 17;
        int slot = atomicAdd(&curL[l], 1);
        col[e0 + slot] = p & 0x1FFFF;
    }
    int total = nNodes * DIM;
    int base64 = nodeBase << 6;
    for (int i = t; i < total; i += 256)
        Xs[base64 + i] = x[base64 + i] * dinvL[i >> 6];
}

// ---------------- fused layer (BYTE-EXACT round-4 structure: proven 70 us, no spill) ----------------
template <bool RELU, bool SCALE_OUT>
__global__ __launch_bounds__(256, 8) void k_layer(const float* __restrict__ In,
                                                  const int* __restrict__ row_ptr,
                                                  const int* __restrict__ col,
                                                  const float* __restrict__ dinv,
                                                  const float* __restrict__ W,
                                                  const float* __restrict__ bias,
                                                  float* __restrict__ Out, int N) {
    __shared__ float WLs[DIM * DIM];     // 16 KB, transposed-quad layout
    __shared__ float4 zL[4 * 16];        // per-wave z staging
    int t = threadIdx.x;
    int lane = t & 63;
    int wave = t >> 6;
    int g = lane >> 4;    // quad group 0..3
    int gl = lane & 15;   // float4 index within a row

    for (int k = wave; k < DIM; k += 4)
        WLs[(k >> 2) * 256 + lane * 4 + (k & 3)] = W[k * DIM + lane];
    __syncthreads();
    const float4* WL4 = (const float4*)WLs;   // WL4[k16*64 + lane]

    float blane = bias[lane];
    const float4* InR = (const float4*)In;    // 16 float4 per row

    int v0 = (blockIdx.x * 4 + wave) * NPW;
    for (int r = 0; r < NPW; ++r) {
        int v = v0 + r;
        if (v >= N) return;
        int e0 = row_ptr[v];
        int e1 = row_ptr[v + 1];
        float dv = dinv[v];
        int d1 = e1 - e0 + 1;  // neighbors + self
        float4 acc0 = make_float4(0.f, 0.f, 0.f, 0.f);
        float4 acc1 = make_float4(0.f, 0.f, 0.f, 0.f);
        float4 acc2 = make_float4(0.f, 0.f, 0.f, 0.f);
        float4 acc3 = make_float4(0.f, 0.f, 0.f, 0.f);
        int base = 0;
        while (base < d1) {
            int m = d1 - base; if (m > 64) m = 64;
            int slot = base + lane;
            int u = v;
            if (slot > 0 && slot < d1) u = col[e0 + slot - 1];
            int nfull = m >> 2;
            int q = 0;
            for (; q + 4 <= nfull; q += 4) {
                int u0 = __shfl(u, (q + 0) * 4 + g, 64);
                int u1 = __shfl(u, (q + 1) * 4 + g, 64);
                int u2 = __shfl(u, (q + 2) * 4 + g, 64);
                int u3 = __shfl(u, (q + 3) * 4 + g, 64);
                float4 a0 = InR[u0 * 16 + gl];
                float4 a1 = InR[u1 * 16 + gl];
                float4 a2 = InR[u2 * 16 + gl];
                float4 a3 = InR[u3 * 16 + gl];
                acc0.x += a0.x; acc0.y += a0.y; acc0.z += a0.z; acc0.w += a0.w;
                acc1.x += a1.x; acc1.y += a1.y; acc1.z += a1.z; acc1.w += a1.w;
                acc2.x += a2.x; acc2.y += a2.y; acc2.z += a2.z; acc2.w += a2.w;
                acc3.x += a3.x; acc3.y += a3.y; acc3.z += a3.z; acc3.w += a3.w;
            }
            for (; q + 2 <= nfull; q += 2) {
                int u0 = __shfl(u, (q + 0) * 4 + g, 64);
                int u1 = __shfl(u, (q + 1) * 4 + g, 64);
                float4 a0 = InR[u0 * 16 + gl];
                float4 a1 = InR[u1 * 16 + gl];
                acc0.x += a0.x; acc0.y += a0.y; acc0.z += a0.z; acc0.w += a0.w;
                acc1.x += a1.x; acc1.y += a1.y; acc1.z += a1.z; acc1.w += a1.w;
            }
            for (; q < nfull; ++q) {
                int u0 = __shfl(u, q * 4 + g, 64);
                float4 a0 = InR[u0 * 16 + gl];
                acc0.x += a0.x; acc0.y += a0.y; acc0.z += a0.z; acc0.w += a0.w;
            }
            if (m & 3) {
                int sidx = nfull * 4 + g;
                bool ok = sidx < m;
                int uu = __shfl(u, ok ? sidx : 0, 64);
                float4 a0 = InR[uu * 16 + gl];
                if (ok) { acc0.x += a0.x; acc0.y += a0.y; acc0.z += a0.z; acc0.w += a0.w; }
            }
            base += m;
        }
        float4 z;
        z.x = (acc0.x + acc1.x) + (acc2.x + acc3.x);
        z.y = (acc0.y + acc1.y) + (acc2.y + acc3.y);
        z.z = (acc0.z + acc1.z) + (acc2.z + acc3.z);
        z.w = (acc0.w + acc1.w) + (acc2.w + acc3.w);
        z.x += __shfl_xor(z.x, 16, 64); z.y += __shfl_xor(z.y, 16, 64);
        z.z += __shfl_xor(z.z, 16, 64); z.w += __shfl_xor(z.w, 16, 64);
        z.x += __shfl_xor(z.x, 32, 64); z.y += __shfl_xor(z.y, 32, 64);
        z.z += __shfl_xor(z.z, 32, 64); z.w += __shfl_xor(z.w, 32, 64);
        if (g == 0) zL[wave * 16 + gl] = z;   // intra-wave, no barrier
        float rdot = 0.f;
#pragma unroll
        for (int k16 = 0; k16 < 16; ++k16) {
            float4 zc = zL[wave * 16 + k16];  // broadcast read
            float4 wv = WL4[k16 * 64 + lane];
            rdot = fmaf(zc.x, wv.x, rdot);
            rdot = fmaf(zc.y, wv.y, rdot);
            rdot = fmaf(zc.z, wv.z, rdot);
            rdot = fmaf(zc.w, wv.w, rdot);
        }
        float h = fmaf(dv, rdot, blane);
        if (RELU) h = fmaxf(h, 0.f);
        if (SCALE_OUT) h *= dv;
        Out[v * DIM + lane] = h;
    }
}

// ---------------- fused mean-pool + linear head ----------------
// One block per graph. batch is sorted; range via binary search. 4 waves sum
// disjoint node strides (lane = feature), LDS cross-wave reduce, then wave 0
// computes out[g] = mean @ Wlin + blin.
__global__ __launch_bounds__(256) void k_poolhead(const float* __restrict__ H,
                                                  const int* __restrict__ batch, int N,
                                                  const float* __restrict__ Wlin,
                                                  const float* __restrict__ blin,
                                                  float* __restrict__ out) {
    __shared__ float partial[4 * DIM];
    __shared__ float meanL[DIM];
    int t = threadIdx.x;
    int lane = t & 63;
    int wave = t >> 6;
    int gph = blockIdx.x;
    // lower_bound(batch, gph) and lower_bound(batch, gph+1)
    int lo = 0, hi = N;
    while (lo < hi) { int mid = (lo + hi) >> 1; if (batch[mid] < gph) lo = mid + 1; else hi = mid; }
    int c0 = lo;
    lo = 0; hi = N;
    int g1 = gph + 1;
    while (lo < hi) { int mid = (lo + hi) >> 1; if (batch[mid] < g1) lo = mid + 1; else hi = mid; }
    int c1 = lo;
    float acc = 0.f;
    for (int i = c0 + wave; i < c1; i += 4)
        acc += H[i * DIM + lane];
    partial[wave * DIM + lane] = acc;
    __syncthreads();
    if (wave == 0) {
        int c = c1 - c0; if (c < 1) c = 1;
        float invc = 1.0f / (float)c;
        float s = partial[lane] + partial[DIM + lane] + partial[2 * DIM + lane] + partial[3 * DIM + lane];
        meanL[lane] = s * invc;
    }
    __syncthreads();
    if (wave == 0) {
        float r = blin[lane];
#pragma unroll
        for (int k = 0; k < DIM; ++k)
            r = fmaf(meanL[k], Wlin[k * DIM + lane], r);
        out[gph * DIM + lane] = r;
    }
}

// ---------------- launch ----------------

extern "C" void kernel_launch(void* const* d_in, const int* in_sizes, int n_in,
                              void* d_out, int out_size, void* d_ws, size_t ws_size,
                              hipStream_t stream) {
    const float* x    = (const float*)d_in[0];
    const int*   edge = (const int*)d_in[1];
    const int*   batch= (const int*)d_in[2];
    const float* W1 = (const float*)d_in[3];
    const float* b1 = (const float*)d_in[4];
    const float* W2 = (const float*)d_in[5];
    const float* b2 = (const float*)d_in[6];
    const float* W3 = (const float*)d_in[7];
    const float* b3 = (const float*)d_in[8];
    const float* Wlin = (const float*)d_in[9];
    const float* blin = (const float*)d_in[10];
    float* out = (float*)d_out;

    int N = in_sizes[0] / DIM;
    int E = in_sizes[1] / 2;
    int G = out_size / DIM;
    const int* srcv = edge;
    const int* dstv = edge + E;
    int B = (N + NB - 1) >> NB_SHIFT;

    char* ws = (char*)d_ws;
    auto alloc = [&](size_t bytes) {
        char* p = ws;
        ws += (bytes + 255) & ~(size_t)255;
        return p;
    };
    int*   bucketCnt    = (int*)alloc((size_t)B * 4);
    int*   bucketOff    = (int*)alloc((size_t)(B + 1) * 4);
    int*   bucketCursor = (int*)alloc((size_t)B * 4);
    int*   pairs        = (int*)alloc((size_t)E * 4);
    int*   row_ptr      = (int*)alloc(((size_t)N + 1) * 4);
    int*   colv         = (int*)alloc((size_t)E * 4);
    float* dinv         = (float*)alloc((size_t)N * 4);
    float* Xs           = (float*)alloc((size_t)N * DIM * 4);
    float* buf0         = (float*)alloc((size_t)N * DIM * 4);
    float* buf1         = (float*)alloc((size_t)N * DIM * 4);

    hipMemsetAsync(bucketCnt, 0, (size_t)B * 4, stream);

    k_binA<<<512, 256, 0, stream>>>(dstv, E, B, bucketCnt);
    k_scanB<<<1, 256, 0, stream>>>(bucketCnt, B, E, N, bucketOff, bucketCursor, row_ptr);
    k_binB<<<(E + TILE - 1) / TILE, 256, 0, stream>>>(srcv, dstv, E, B, bucketCursor, pairs);
    k_buildCSR<<<B, 256, 0, stream>>>(pairs, bucketOff, N, row_ptr, colv, dinv, x, Xs);

    int layerBlocks = (N + 4 * NPW - 1) / (4 * NPW);

    k_layer<true, true><<<layerBlocks, 256, 0, stream>>>(Xs, row_ptr, colv, dinv, W1, b1, buf0, N);
    k_layer<true, true><<<layerBlocks, 256, 0, stream>>>(buf0, row_ptr, colv, dinv, W2, b2, buf1, N);
    k_layer<false, false><<<layerBlocks, 256, 0, stream>>>(buf1, row_ptr, colv, dinv, W3, b3, buf0, N);

    k_poolhead<<<G, 256, 0, stream>>>(buf0, batch, N, Wlin, blin, out);
}